// Round 4
// baseline (451.527 us; speedup 1.0000x reference)
//
#include <hip/hip_runtime.h>
#include <math.h>

// Sparsemax along axis 0 of z = -exp(a)*x, x: (4096, 8192) f32 row-major.
//
// R6b: same as R6, fixing the nontemporal-store compile error (builtin
// requires a native vector type, not HIP_vector_type).
//
// R6 design: contiguous-geometry K1 + atomic-free candidate slots + nt stores.
// R5 post-mortem: harness fills (512MiB @ 6.8 TB/s, ~80us x2) are fixed
// overhead ~160us; our kernel budget is ~105us vs a ~65us floor. Suspect:
// K1's wave-load was 8 SCATTERED 128B segments (rows 32KB apart) -> ~2-3
// TB/s effective (R4's 16x64B pattern measured ~2.1 TB/s), while contiguous
// streams hit 6.3-6.8 TB/s (fills, m13).
//
// K1 redesign: thread owns 4 CONSECUTIVE cols over a 64-row sub-strip; a
// wave-load is ONE contiguous 1024B segment. Column-max accumulates in 4
// registers (no shuffles). Filter is a 2nd local pass over the same 256KB
// strip (L2/L3-hot). Candidates go to deterministic per-(chunk,col) slot
// ranges via LDS counters -> no global atomics, no memset dispatch.
// Chunk = 256 rows: E[cands per chunk-col] ~ 2.3, CAP=12 -> overflow
// probability ~1e-6; overflow -> exact full-column fallback in K2
// (correctness never depends on statistics).
//
// K2: one wave/col Michelot on <=192 slots (3/lane). Exact; converges from
// below since all filtered-out elements are provably <= tau*.
// K3: contiguous grid-stride epilogue, NON-TEMPORAL stores (don't evict
// L3-resident x with the output stream).
//
// ws layout: [0,512K) ccnt int[16][8192]; [512K,544K) tau f32[8192];
//            [1M, 1M+6M) cand f32[8192][192].

constexpr int ROWS = 4096;
constexpr int COLS = 8192;

constexpr int CB   = 256;          // cols per K1 block
constexpr int RB   = 256;          // rows per K1 block (= filter chunk)
constexpr int T1   = 256;
constexpr int SUBR = RB / 4;       // 64 rows per sub-group
constexpr int NRB  = ROWS / RB;    // 16 row chunks
constexpr int NCB  = COLS / CB;    // 32 col blocks
constexpr int CAP  = 12;           // candidate slots per (col, chunk)
constexpr int SLOTS = NRB * CAP;   // 192 slots per col

typedef float vfloat4 __attribute__((ext_vector_type(4)));

// ---------------- K1: contiguous streaming max + filter ----------------
__global__ __launch_bounds__(T1, 2)
void k1_maxfilter(const float* __restrict__ x, const float* __restrict__ a,
                  int* __restrict__ ccnt, float* __restrict__ cand)
{
    __shared__ float smax[4][CB];   // per-sub column maxima
    __shared__ float thrS[CB];      // chunkmax - 1 per col
    __shared__ int   lcnt[CB];      // per-col candidate counters

    const int tid = threadIdx.x;
    const int l   = tid & 63;
    const int sub = tid >> 6;

    const int  colb = blockIdx.x * CB;
    const int  row0 = blockIdx.y * RB + sub * SUBR;
    const long base = (long)row0 * COLS + colb + 4 * l;
    const float s   = -expf(a[0]);

    // pass 1: 64 rows x 4 owned cols; wave instr = one 1024B contiguous line
    float pm0 = -3e38f, pm1 = -3e38f, pm2 = -3e38f, pm3 = -3e38f;
#pragma unroll 8
    for (int k = 0; k < SUBR; ++k) {
        const float4 v = *reinterpret_cast<const float4*>(x + base + (long)k * COLS);
        pm0 = fmaxf(pm0, s * v.x);
        pm1 = fmaxf(pm1, s * v.y);
        pm2 = fmaxf(pm2, s * v.z);
        pm3 = fmaxf(pm3, s * v.w);
    }
    smax[sub][4 * l + 0] = pm0;
    smax[sub][4 * l + 1] = pm1;
    smax[sub][4 * l + 2] = pm2;
    smax[sub][4 * l + 3] = pm3;
    __syncthreads();
    // combine the 4 sub-strips; set threshold; zero counters
    {
        float m = fmaxf(fmaxf(smax[0][tid], smax[1][tid]),
                        fmaxf(smax[2][tid], smax[3][tid]));
        thrS[tid] = m - 1.0f;
        lcnt[tid] = 0;
    }
    __syncthreads();

    // pass 2: re-read the strip (L2/L3-hot), append candidates to global slots
    const float t0 = thrS[4 * l + 0];
    const float t1 = thrS[4 * l + 1];
    const float t2 = thrS[4 * l + 2];
    const float t3 = thrS[4 * l + 3];
    const long  slotbase = (long)blockIdx.y * CAP;   // chunk's slot range
    for (int k = 0; k < SUBR; ++k) {
        const float4 v = *reinterpret_cast<const float4*>(x + base + (long)k * COLS);
        const float z0 = s * v.x, z1 = s * v.y, z2 = s * v.z, z3 = s * v.w;
        if (z0 > t0) { int i = atomicAdd(&lcnt[4*l+0], 1);
                       if (i < CAP) cand[(long)(colb+4*l+0) * SLOTS + slotbase + i] = z0; }
        if (z1 > t1) { int i = atomicAdd(&lcnt[4*l+1], 1);
                       if (i < CAP) cand[(long)(colb+4*l+1) * SLOTS + slotbase + i] = z1; }
        if (z2 > t2) { int i = atomicAdd(&lcnt[4*l+2], 1);
                       if (i < CAP) cand[(long)(colb+4*l+2) * SLOTS + slotbase + i] = z2; }
        if (z3 > t3) { int i = atomicAdd(&lcnt[4*l+3], 1);
                       if (i < CAP) cand[(long)(colb+4*l+3) * SLOTS + slotbase + i] = z3; }
    }
    __syncthreads();
    // publish raw counts (solver detects >CAP as overflow)
    ccnt[blockIdx.y * COLS + colb + tid] = lcnt[tid];
}

// ---------------- K2: one wave per column, Michelot ----------------
__global__ __launch_bounds__(256, 4)
void k2_solve(const int* __restrict__ ccnt, const float* __restrict__ cand,
              const float* __restrict__ x, const float* __restrict__ a,
              float* __restrict__ tau)
{
    const int lane = threadIdx.x & 63;
    const int wv   = threadIdx.x >> 6;
    const int col  = blockIdx.x * 4 + wv;

    // gather 3 slots/lane; validity from per-chunk counts
    bool ovf = false;
    float v0 = -3.3e38f, v1 = -3.3e38f, v2 = -3.3e38f;
    {
        const int s0 = lane, s1 = lane + 64, s2 = lane + 128;
        const int n0 = ccnt[(s0 / CAP) * COLS + col];
        const int n1 = ccnt[(s1 / CAP) * COLS + col];
        const int n2 = ccnt[(s2 / CAP) * COLS + col];
        ovf = (n0 > CAP) | (n1 > CAP) | (n2 > CAP);
        const float c0 = cand[(long)col * SLOTS + s0];
        const float c1 = cand[(long)col * SLOTS + s1];
        const float c2 = cand[(long)col * SLOTS + s2];
        if ((s0 % CAP) < n0) v0 = c0;
        if ((s1 % CAP) < n1) v1 = c1;
        if ((s2 % CAP) < n2) v2 = c2;
    }

    float t = -3.0e38f;
    if (!__any(ovf)) {
        // exact Michelot on the candidate superset (converges from below)
        float prev = 0.f;
        for (int it = 0; it < 200; ++it) {
            float ss = 0.f, sc = 0.f;
            if (v0 > t) { ss += v0; sc += 1.f; }
            if (v1 > t) { ss += v1; sc += 1.f; }
            if (v2 > t) { ss += v2; sc += 1.f; }
#pragma unroll
            for (int m = 1; m < 64; m <<= 1) {
                ss += __shfl_xor(ss, m, 64);
                sc += __shfl_xor(sc, m, 64);
            }
            t = (ss - 1.0f) / sc;           // sc >= 1 (chunk maxima present)
            if (sc == prev) break;
            prev = sc;
        }
    } else {
        // overflow fallback: exact Michelot over the full column (L3-hot)
        const float s = -expf(a[0]);
        float prev = 0.f;
        for (int it = 0; it < 256; ++it) {
            float ss = 0.f, sc = 0.f;
            for (int i = 0; i < ROWS / 64; ++i) {
                const float zz = s * x[(long)(lane + i * 64) * COLS + col];
                if (zz > t) { ss += zz; sc += 1.f; }
            }
#pragma unroll
            for (int m = 1; m < 64; m <<= 1) {
                ss += __shfl_xor(ss, m, 64);
                sc += __shfl_xor(sc, m, 64);
            }
            t = (ss - 1.0f) / sc;
            if (sc == prev) break;
            prev = sc;
        }
    }
    if (lane == 0) tau[col] = t;
}

// ---------------- K3: streaming epilogue (nt stores) ----------------
__global__ __launch_bounds__(256, 8)
void k3_epilogue(const float* __restrict__ x, const float* __restrict__ a,
                 const float* __restrict__ tau, float* __restrict__ out)
{
    const float s = -expf(a[0]);
    const float4*  x4 = reinterpret_cast<const float4*>(x);
    const float4*  t4 = reinterpret_cast<const float4*>(tau);
    vfloat4*       o4 = reinterpret_cast<vfloat4*>(out);
    const int N4 = ROWS * (COLS / 4);
    const int stride = gridDim.x * blockDim.x;
    for (int i = blockIdx.x * blockDim.x + threadIdx.x; i < N4; i += stride) {
        const float4 v  = x4[i];
        const float4 tt = t4[i & (COLS / 4 - 1)];
        vfloat4 o;
        o.x = fmaxf(fmaf(s, v.x, -tt.x), 0.f);
        o.y = fmaxf(fmaf(s, v.y, -tt.y), 0.f);
        o.z = fmaxf(fmaf(s, v.z, -tt.z), 0.f);
        o.w = fmaxf(fmaf(s, v.w, -tt.w), 0.f);
        __builtin_nontemporal_store(o, &o4[i]);
    }
}

extern "C" void kernel_launch(void* const* d_in, const int* in_sizes, int n_in,
                              void* d_out, int out_size, void* d_ws, size_t ws_size,
                              hipStream_t stream) {
    const float* x = (const float*)d_in[0];
    const float* a = (const float*)d_in[1];
    float* out = (float*)d_out;

    char*  ws   = (char*)d_ws;
    int*   ccnt = (int*)ws;                            // 512 KB, fully written by K1
    float* tau  = (float*)(ws + 512 * 1024);           // 32 KB
    float* cand = (float*)(ws + 1024 * 1024);          // 6 MiB

    hipLaunchKernelGGL(k1_maxfilter, dim3(NCB, NRB), dim3(T1), 0, stream,
                       x, a, ccnt, cand);
    hipLaunchKernelGGL(k2_solve, dim3(COLS / 4), dim3(256), 0, stream,
                       ccnt, cand, x, a, tau);
    hipLaunchKernelGGL(k3_epilogue, dim3(2048), dim3(256), 0, stream,
                       x, a, tau, out);
}

// Round 5
// 424.274 us; speedup vs baseline: 1.0642x; 1.0642x over previous
//
#include <hip/hip_runtime.h>
#include <math.h>

// Sparsemax along axis 0 of z = -exp(a)*x, x: (4096, 8192) f32 row-major.
//
// R7: revert K2 to the R5-proven per-column candidate list; keep R6's
// contiguous K1 geometry and K3 nt stores.
//
// R6 post-mortem: the per-chunk-slot K2 ran its column-strided full-column
// fallback for a large fraction of columns (FETCH 356MB, 178us, ~2TB/s
// scatter) despite statistics saying overflow should be ~0 -- the
// deterministic-slot/count plumbing mis-triggers. R5's K2 (global atomic
// per-column list, CAP=64) was measured fast (<<80us). Revert to that.
//
// Structure:
//   K1 (contiguous): thread owns 4 consecutive cols over a 64-row strip;
//       wave load = one 1024B contiguous segment. Pass 1: col-max in 4
//       registers (no shuffles). Pass 2 (L2/L3-hot re-read): append
//       z > chunkmax-1 (256-row chunk) to per-column global list via
//       atomicAdd(cnt[col]). Superset of support since chunkmax <= colmax
//       => tau* >= colmax-1 >= chunkmax-1.
//       E[cands/col] ~ 29, CAP=64 -> P(overflow) ~ 1e-9 per col.
//   K2: one wave per column, exact Michelot on <=64 candidates (1/lane);
//       full-column fallback only on overflow (correctness never depends
//       on statistics).
//   K3: contiguous grid-stride epilogue out = max(s*x - tau[col], 0),
//       NON-TEMPORAL stores (output is write-once; don't evict L3-hot x).
//
// ws layout: [0,32K) cnt int[8192]; [32K,64K) tau f32[8192];
//            [64K,64K+2M) cand f32[8192][64].

constexpr int ROWS = 4096;
constexpr int COLS = 8192;

constexpr int CB   = 256;          // cols per K1 block
constexpr int RB   = 256;          // rows per K1 block (= filter chunk)
constexpr int T1   = 256;
constexpr int SUBR = RB / 4;       // 64 rows per sub-group
constexpr int NRB  = ROWS / RB;    // 16 row chunks
constexpr int NCB  = COLS / CB;    // 32 col blocks
constexpr int CAPC = 64;           // candidate slots per column

typedef float vfloat4 __attribute__((ext_vector_type(4)));

// ---------------- K1: contiguous streaming max + filter ----------------
__global__ __launch_bounds__(T1, 2)
void k1_maxfilter(const float* __restrict__ x, const float* __restrict__ a,
                  int* __restrict__ cnt, float* __restrict__ cand)
{
    __shared__ float smax[4][CB];   // per-sub column maxima
    __shared__ float thrS[CB];      // chunkmax - 1 per col

    const int tid = threadIdx.x;
    const int l   = tid & 63;
    const int sub = tid >> 6;

    const int  colb = blockIdx.x * CB;
    const int  row0 = blockIdx.y * RB + sub * SUBR;
    const long base = (long)row0 * COLS + colb + 4 * l;
    const float s   = -expf(a[0]);

    // pass 1: 64 rows x 4 owned cols; wave instr = one 1024B contiguous line
    float pm0 = -3e38f, pm1 = -3e38f, pm2 = -3e38f, pm3 = -3e38f;
#pragma unroll 8
    for (int k = 0; k < SUBR; ++k) {
        const float4 v = *reinterpret_cast<const float4*>(x + base + (long)k * COLS);
        pm0 = fmaxf(pm0, s * v.x);
        pm1 = fmaxf(pm1, s * v.y);
        pm2 = fmaxf(pm2, s * v.z);
        pm3 = fmaxf(pm3, s * v.w);
    }
    smax[sub][4 * l + 0] = pm0;
    smax[sub][4 * l + 1] = pm1;
    smax[sub][4 * l + 2] = pm2;
    smax[sub][4 * l + 3] = pm3;
    __syncthreads();
    // combine the 4 sub-strips into the chunk threshold
    thrS[tid] = fmaxf(fmaxf(smax[0][tid], smax[1][tid]),
                      fmaxf(smax[2][tid], smax[3][tid])) - 1.0f;
    __syncthreads();

    // pass 2: re-read the strip (L2/L3-hot), append candidates to the
    // per-column global list (single atomic counter per column)
    const float t0 = thrS[4 * l + 0];
    const float t1 = thrS[4 * l + 1];
    const float t2 = thrS[4 * l + 2];
    const float t3 = thrS[4 * l + 3];
    const int c0 = colb + 4 * l;
    for (int k = 0; k < SUBR; ++k) {
        const float4 v = *reinterpret_cast<const float4*>(x + base + (long)k * COLS);
        const float z0 = s * v.x, z1 = s * v.y, z2 = s * v.z, z3 = s * v.w;
        if (z0 > t0) { int i = atomicAdd(&cnt[c0 + 0], 1);
                       if (i < CAPC) cand[(long)(c0 + 0) * CAPC + i] = z0; }
        if (z1 > t1) { int i = atomicAdd(&cnt[c0 + 1], 1);
                       if (i < CAPC) cand[(long)(c0 + 1) * CAPC + i] = z1; }
        if (z2 > t2) { int i = atomicAdd(&cnt[c0 + 2], 1);
                       if (i < CAPC) cand[(long)(c0 + 2) * CAPC + i] = z2; }
        if (z3 > t3) { int i = atomicAdd(&cnt[c0 + 3], 1);
                       if (i < CAPC) cand[(long)(c0 + 3) * CAPC + i] = z3; }
    }
}

// ---------------- K2: one wave per column, Michelot ----------------
__global__ __launch_bounds__(256, 4)
void k2_solve(const int* __restrict__ cnt, const float* __restrict__ cand,
              const float* __restrict__ x, const float* __restrict__ a,
              float* __restrict__ tau)
{
    const int lane = threadIdx.x & 63;
    const int wv   = threadIdx.x >> 6;
    const int col  = blockIdx.x * 4 + wv;
    const int K    = cnt[col];

    float t = -3.0e38f;
    if (K <= CAPC) {
        // exact Michelot on the candidate superset (1 value/lane)
        const float v = (lane < K) ? cand[(long)col * CAPC + lane] : -3.3e38f;
        float prev = 0.f;
        for (int it = 0; it < CAPC + 4; ++it) {
            const bool act = v > t;
            float ss = act ? v : 0.f;
            float sc = act ? 1.f : 0.f;
#pragma unroll
            for (int m = 1; m < 64; m <<= 1) {
                ss += __shfl_xor(ss, m, 64);
                sc += __shfl_xor(sc, m, 64);
            }
            t = (ss - 1.0f) / sc;           // sc >= 1 (chunk maxima present)
            if (sc == prev) break;
            prev = sc;
        }
    } else {
        // overflow fallback: exact Michelot over the full column
        const float s = -expf(a[0]);
        float prev = 0.f;
        for (int it = 0; it < 256; ++it) {
            float ss = 0.f, sc = 0.f;
            for (int i = 0; i < ROWS / 64; ++i) {
                const float zz = s * x[(long)(lane + i * 64) * COLS + col];
                if (zz > t) { ss += zz; sc += 1.f; }
            }
#pragma unroll
            for (int m = 1; m < 64; m <<= 1) {
                ss += __shfl_xor(ss, m, 64);
                sc += __shfl_xor(sc, m, 64);
            }
            t = (ss - 1.0f) / sc;
            if (sc == prev) break;
            prev = sc;
        }
    }
    if (lane == 0) tau[col] = t;
}

// ---------------- K3: streaming epilogue (nt stores) ----------------
__global__ __launch_bounds__(256, 8)
void k3_epilogue(const float* __restrict__ x, const float* __restrict__ a,
                 const float* __restrict__ tau, float* __restrict__ out)
{
    const float s = -expf(a[0]);
    const float4*  x4 = reinterpret_cast<const float4*>(x);
    const float4*  t4 = reinterpret_cast<const float4*>(tau);
    vfloat4*       o4 = reinterpret_cast<vfloat4*>(out);
    const int N4 = ROWS * (COLS / 4);
    const int stride = gridDim.x * blockDim.x;
    for (int i = blockIdx.x * blockDim.x + threadIdx.x; i < N4; i += stride) {
        const float4 v  = x4[i];
        const float4 tt = t4[i & (COLS / 4 - 1)];
        vfloat4 o;
        o.x = fmaxf(fmaf(s, v.x, -tt.x), 0.f);
        o.y = fmaxf(fmaf(s, v.y, -tt.y), 0.f);
        o.z = fmaxf(fmaf(s, v.z, -tt.z), 0.f);
        o.w = fmaxf(fmaf(s, v.w, -tt.w), 0.f);
        __builtin_nontemporal_store(o, &o4[i]);
    }
}

extern "C" void kernel_launch(void* const* d_in, const int* in_sizes, int n_in,
                              void* d_out, int out_size, void* d_ws, size_t ws_size,
                              hipStream_t stream) {
    const float* x = (const float*)d_in[0];
    const float* a = (const float*)d_in[1];
    float* out = (float*)d_out;

    char*  ws   = (char*)d_ws;
    int*   cnt  = (int*)ws;                       // 32 KB
    float* tau  = (float*)(ws + 32 * 1024);       // 32 KB
    float* cand = (float*)(ws + 64 * 1024);       // 2 MiB

    hipMemsetAsync(cnt, 0, COLS * sizeof(int), stream);
    hipLaunchKernelGGL(k1_maxfilter, dim3(NCB, NRB), dim3(T1), 0, stream,
                       x, a, cnt, cand);
    hipLaunchKernelGGL(k2_solve, dim3(COLS / 4), dim3(256), 0, stream,
                       cnt, cand, x, a, tau);
    hipLaunchKernelGGL(k3_epilogue, dim3(2048), dim3(256), 0, stream,
                       x, a, tau, out);
}

// Round 6
// 315.124 us; speedup vs baseline: 1.4329x; 1.3464x over previous
//
#include <hip/hip_runtime.h>
#include <math.h>

// Sparsemax along axis 0 of z = -exp(a)*x, x: (4096, 8192) f32 row-major.
//
// R8: sparse-output restructure.
//   Facts from R5/R7: (a) parallelism beats contiguity -- R7's contiguous
//   k1 at 2 blocks/CU ran 1.1 TB/s / 130us; R5's scattered k1 at 4x waves
//   was <79us. (b) output is ~99.9% zeros (support ~5 of 4096 per col), so
//   a full streaming epilogue (read+write 256 MiB) is wasted motion.
// Structure:
//   memset(out,0)  -- 128 MiB fill ~20us (engine rate ~6.5 TB/s)
//   K1: ONE-PASS max+filter. 512 thr, 2048 blocks (256 cols x 64 rows per
//       block; thread owns 4 consecutive cols x 8 rows = 32 regs). Wave
//       load = one contiguous 1024B segment AND 4 blocks/CU occupancy.
//       Filter: z > chunkmax-1 (64-row chunk) is a SUPERSET of support
//       (tau* >= colmax-1 >= chunkmax-1). Appends (value,row) pairs to
//       per-column global lists. E~98 cands/col (sigma_z=e: threshold is
//       0.368 sigma below chunk max), CAP=192 (+9 sigma margin).
//   K2: one wave/col: 3-deep Michelot on the list, then SCATTER-writes the
//       ~5 nonzeros (out[row,col] = v - tau). Overflow -> exact full-column
//       fallback incl. scatter (correctness never depends on statistics).
// ws: [0,32K) cnt int[8192]; [64K, 64K+12.6M) cand float2[8192][192].

constexpr int ROWS = 4096;
constexpr int COLS = 8192;

constexpr int CB   = 256;           // cols per K1 block
constexpr int RB   = 64;            // rows per K1 block (= filter chunk)
constexpr int T1   = 512;           // 8 subs x 64 lanes
constexpr int RPT  = RB / 8;        // 8 rows per thread
constexpr int CAPC = 192;           // candidate slots per column

// ---------------- K1: one-pass contiguous max + filter ----------------
__global__ __launch_bounds__(T1, 4)
void k1_maxfilter(const float* __restrict__ x, const float* __restrict__ a,
                  int* __restrict__ cnt, float2* __restrict__ cand)
{
    __shared__ float smax[8][CB];   // per-sub column maxima (8 KB)
    __shared__ float thrS[CB];      // chunkmax - 1 per col

    const int tid = threadIdx.x;
    const int l   = tid & 63;
    const int sub = tid >> 6;

    const int  colb = blockIdx.x * CB;
    const int  row0 = blockIdx.y * RB + sub * RPT;
    const long base = (long)row0 * COLS + colb + 4 * l;
    const float s   = -expf(a[0]);

    // one load pass: 8 rows x 4 owned cols; wave instr = 1024B contiguous
    float z[RPT][4];
#pragma unroll
    for (int k = 0; k < RPT; ++k) {
        const float4 v = *reinterpret_cast<const float4*>(x + base + (long)k * COLS);
        z[k][0] = s * v.x; z[k][1] = s * v.y;
        z[k][2] = s * v.z; z[k][3] = s * v.w;
    }

    // per-column max across own rows (registers, no shuffles)
    float pm[4] = {z[0][0], z[0][1], z[0][2], z[0][3]};
#pragma unroll
    for (int k = 1; k < RPT; ++k)
#pragma unroll
        for (int c = 0; c < 4; ++c) pm[c] = fmaxf(pm[c], z[k][c]);
#pragma unroll
    for (int c = 0; c < 4; ++c) smax[sub][4 * l + c] = pm[c];
    __syncthreads();
    if (tid < CB) {
        float m = smax[0][tid];
#pragma unroll
        for (int w = 1; w < 8; ++w) m = fmaxf(m, smax[w][tid]);
        thrS[tid] = m - 1.0f;
    }
    __syncthreads();

    // filter from registers; append (value, row) to per-column global list
    const float t0 = thrS[4 * l + 0];
    const float t1 = thrS[4 * l + 1];
    const float t2 = thrS[4 * l + 2];
    const float t3 = thrS[4 * l + 3];
    const int c0 = colb + 4 * l;
#pragma unroll
    for (int k = 0; k < RPT; ++k) {
        const int row = row0 + k;
        const float fr = __int_as_float(row);
        if (z[k][0] > t0) { int i = atomicAdd(&cnt[c0 + 0], 1);
            if (i < CAPC) cand[(long)(c0 + 0) * CAPC + i] = make_float2(z[k][0], fr); }
        if (z[k][1] > t1) { int i = atomicAdd(&cnt[c0 + 1], 1);
            if (i < CAPC) cand[(long)(c0 + 1) * CAPC + i] = make_float2(z[k][1], fr); }
        if (z[k][2] > t2) { int i = atomicAdd(&cnt[c0 + 2], 1);
            if (i < CAPC) cand[(long)(c0 + 2) * CAPC + i] = make_float2(z[k][2], fr); }
        if (z[k][3] > t3) { int i = atomicAdd(&cnt[c0 + 3], 1);
            if (i < CAPC) cand[(long)(c0 + 3) * CAPC + i] = make_float2(z[k][3], fr); }
    }
}

// ---------------- K2: one wave per column, Michelot + scatter ----------------
__global__ __launch_bounds__(256, 4)
void k2_solve_scatter(const int* __restrict__ cnt, const float2* __restrict__ cand,
                      const float* __restrict__ x, const float* __restrict__ a,
                      float* __restrict__ out)
{
    const int lane = threadIdx.x & 63;
    const int wv   = threadIdx.x >> 6;
    const int col  = blockIdx.x * 4 + wv;
    const int K    = cnt[col];

    if (K <= CAPC) {
        // gather 3 slots/lane (wave reads 3 x 512B contiguous)
        const int s0 = lane, s1 = lane + 64, s2 = lane + 128;
        float v0 = -3.3e38f, v1 = -3.3e38f, v2 = -3.3e38f;
        int   r0 = 0, r1 = 0, r2 = 0;
        const long cbase = (long)col * CAPC;
        if (s0 < K) { float2 p = cand[cbase + s0]; v0 = p.x; r0 = __float_as_int(p.y); }
        if (s1 < K) { float2 p = cand[cbase + s1]; v1 = p.x; r1 = __float_as_int(p.y); }
        if (s2 < K) { float2 p = cand[cbase + s2]; v2 = p.x; r2 = __float_as_int(p.y); }

        // exact Michelot on the candidate superset (converges from below)
        float t = -3.0e38f, prev = 0.f;
        for (int it = 0; it < CAPC + 4; ++it) {
            float ss = 0.f, sc = 0.f;
            if (v0 > t) { ss += v0; sc += 1.f; }
            if (v1 > t) { ss += v1; sc += 1.f; }
            if (v2 > t) { ss += v2; sc += 1.f; }
#pragma unroll
            for (int m = 1; m < 64; m <<= 1) {
                ss += __shfl_xor(ss, m, 64);
                sc += __shfl_xor(sc, m, 64);
            }
            t = (ss - 1.0f) / sc;           // sc >= 1 (chunk maxima present)
            if (sc == prev) break;
            prev = sc;
        }
        // scatter the support (out is pre-zeroed)
        if (v0 > t) out[(long)r0 * COLS + col] = v0 - t;
        if (v1 > t) out[(long)r1 * COLS + col] = v1 - t;
        if (v2 > t) out[(long)r2 * COLS + col] = v2 - t;
    } else {
        // overflow fallback: exact Michelot over the full column + scatter
        const float s = -expf(a[0]);
        float t = -3.0e38f, prev = 0.f;
        for (int it = 0; it < 256; ++it) {
            float ss = 0.f, sc = 0.f;
            for (int i = 0; i < ROWS / 64; ++i) {
                const float zz = s * x[(long)(lane + i * 64) * COLS + col];
                if (zz > t) { ss += zz; sc += 1.f; }
            }
#pragma unroll
            for (int m = 1; m < 64; m <<= 1) {
                ss += __shfl_xor(ss, m, 64);
                sc += __shfl_xor(sc, m, 64);
            }
            t = (ss - 1.0f) / sc;
            if (sc == prev) break;
            prev = sc;
        }
        for (int i = 0; i < ROWS / 64; ++i) {
            const long r = lane + i * 64;
            const float zz = s * x[r * COLS + col];
            if (zz > t) out[r * COLS + col] = zz - t;
        }
    }
}

extern "C" void kernel_launch(void* const* d_in, const int* in_sizes, int n_in,
                              void* d_out, int out_size, void* d_ws, size_t ws_size,
                              hipStream_t stream) {
    const float* x = (const float*)d_in[0];
    const float* a = (const float*)d_in[1];
    float* out = (float*)d_out;

    char*   ws   = (char*)d_ws;
    int*    cnt  = (int*)ws;                       // 32 KB
    float2* cand = (float2*)(ws + 64 * 1024);      // 12.6 MiB

    hipMemsetAsync(cnt, 0, COLS * sizeof(int), stream);
    hipMemsetAsync(out, 0, (size_t)ROWS * COLS * sizeof(float), stream);
    hipLaunchKernelGGL(k1_maxfilter, dim3(COLS / CB, ROWS / RB), dim3(T1), 0, stream,
                       x, a, cnt, cand);
    hipLaunchKernelGGL(k2_solve_scatter, dim3(COLS / 4), dim3(256), 0, stream,
                       cnt, cand, x, a, out);
}

// Round 8
// 264.444 us; speedup vs baseline: 1.7075x; 1.1916x over previous
//
#include <hip/hip_runtime.h>
#include <math.h>

// Sparsemax along axis 0 of z = -exp(a)*x, x: (4096, 8192) f32 row-major.
//
// R9 (resubmit after container infra failure): all heavy passes are PURE
// SEQUENTIAL streams.
// Evidence across R4-R8: every kernel whose wave-loads stride at 32KB
// (row-to-row) plateaus at ~1-2 TB/s regardless of segment size (64B/128B/
// 1KB), occupancy (19%/50%), or atomics; only long sequential streams hit
// 6+ TB/s (harness fills 6.8, m13 6.3). So: never stride in a bulk pass.
//
//   A k_pmax:   256 blocks x 1024thr; block = 16-row panel read fully
//               sequentially (512KB); each col owned by exactly one thread
//               -> col-min of x in 8 regs, coalesced write pminx[256][8192].
//               (s = -exp(a) < 0 always => colmax(z) = s * colmin(x).)
//   B k_reduce: 256 partials -> thrx[col] = (s*minx - 1.000002)/s (x-units;
//               z > colmax-1 <=> x < thrx; 2e-6 margin absorbs f32 rounding
//               so candidates remain a STRICT SUPERSET of the support).
//   C k_filter: 512 blocks x 8-row panels, sequential re-read (L3-hot),
//               thresholds in 32KB LDS, compare-only per element; ~4.5
//               candidates/col scattered as (z,row) pairs; cnt padded to
//               64B/counter (atomic line ping-pong avoidance).
//   D k_solve:  one wave/col exact Michelot on <=64 candidates, scatter
//               ~5 nonzeros into pre-zeroed out. K>64 -> exact full-column
//               fallback (correctness never depends on statistics).
//   out is produced by hipMemsetAsync (output is ~99.9% zeros).
//
// ws: [0,512K) cnt int[8192*16]; [512K,544K) thrx f32[8192];
//     [1M,9M) pminx f32[256][8192]; [9M,13M) cand float2[8192][64].

constexpr int ROWS = 4096;
constexpr int COLS = 8192;
constexpr int CAPC = 64;           // candidate slots per column
constexpr int CPAD = 16;           // cnt stride (ints) = one 64B line per col

constexpr int PANA = 16;           // rows per A panel
constexpr int NPA  = ROWS / PANA;  // 256 partials
constexpr int PANC = 8;            // rows per C panel

// ---------------- A: sequential col-min partials ----------------
__global__ __launch_bounds__(1024)
void k_pmax(const float* __restrict__ x, float* __restrict__ pminx)
{
    const int t = threadIdx.x;
    const int b = blockIdx.x;
    const long row0 = (long)b * PANA;

    float m[2][4];
#pragma unroll
    for (int ch = 0; ch < 2; ++ch)
#pragma unroll
        for (int j = 0; j < 4; ++j) m[ch][j] = 3.0e38f;

    for (int r = 0; r < PANA; ++r) {
        const long rb = (row0 + r) * COLS;
#pragma unroll
        for (int ch = 0; ch < 2; ++ch) {
            const int col = ch * 4096 + t * 4;
            const float4 v = *reinterpret_cast<const float4*>(x + rb + col);
            m[ch][0] = fminf(m[ch][0], v.x);
            m[ch][1] = fminf(m[ch][1], v.y);
            m[ch][2] = fminf(m[ch][2], v.z);
            m[ch][3] = fminf(m[ch][3], v.w);
        }
    }
#pragma unroll
    for (int ch = 0; ch < 2; ++ch) {
        float4 o = make_float4(m[ch][0], m[ch][1], m[ch][2], m[ch][3]);
        *reinterpret_cast<float4*>(pminx + (long)b * COLS + ch * 4096 + t * 4) = o;
    }
}

// ---------------- B: reduce partials -> per-col threshold (x-units) -------
__global__ __launch_bounds__(256)
void k_reduce(const float* __restrict__ pminx, const float* __restrict__ a,
              float* __restrict__ thrx)
{
    __shared__ float red[8][33];
    const int t  = threadIdx.x;
    const int c  = t & 31;
    const int sl = t >> 5;
    const int col = blockIdx.x * 32 + c;

    float m = 3.0e38f;
    for (int p = sl * 32; p < sl * 32 + 32; ++p)
        m = fminf(m, pminx[(long)p * COLS + col]);
    red[sl][c] = m;
    __syncthreads();
    if (t < 32) {
        float mm = red[0][t];
#pragma unroll
        for (int k = 1; k < 8; ++k) mm = fminf(mm, red[k][t]);
        const float s = -expf(a[0]);            // s < 0
        // z > colmax_z - 1  <=>  x < (colmax_z - 1)/s ; extra 2e-6 margin
        thrx[blockIdx.x * 32 + t] = (s * mm - 1.000002f) / s;
    }
}

// ---------------- C: sequential filter scan, scatter candidates ----------
__global__ __launch_bounds__(512, 2)
void k_filter(const float* __restrict__ x, const float* __restrict__ a,
              const float* __restrict__ thrx,
              int* __restrict__ cnt, float2* __restrict__ cand)
{
    __shared__ float tl[COLS];      // 32 KB of per-col thresholds
    const int t = threadIdx.x;
    for (int i = t; i < COLS / 4; i += 512)
        reinterpret_cast<float4*>(tl)[i] =
            reinterpret_cast<const float4*>(thrx)[i];
    __syncthreads();

    const long row0 = (long)blockIdx.x * PANC;
    const float s   = -expf(a[0]);

    for (int r = 0; r < PANC; ++r) {
        const int  row = (int)row0 + r;
        const long rb  = (long)row * COLS;
#pragma unroll
        for (int ch = 0; ch < 4; ++ch) {
            const int col = ch * 2048 + t * 4;
            const float4 v  = *reinterpret_cast<const float4*>(x + rb + col);
            const float4 th = *reinterpret_cast<const float4*>(tl + col);
            if (v.x < th.x) { int i = atomicAdd(&cnt[(col + 0) * CPAD], 1);
                if (i < CAPC) cand[(long)(col + 0) * CAPC + i] =
                    make_float2(s * v.x, __int_as_float(row)); }
            if (v.y < th.y) { int i = atomicAdd(&cnt[(col + 1) * CPAD], 1);
                if (i < CAPC) cand[(long)(col + 1) * CAPC + i] =
                    make_float2(s * v.y, __int_as_float(row)); }
            if (v.z < th.z) { int i = atomicAdd(&cnt[(col + 2) * CPAD], 1);
                if (i < CAPC) cand[(long)(col + 2) * CAPC + i] =
                    make_float2(s * v.z, __int_as_float(row)); }
            if (v.w < th.w) { int i = atomicAdd(&cnt[(col + 3) * CPAD], 1);
                if (i < CAPC) cand[(long)(col + 3) * CAPC + i] =
                    make_float2(s * v.w, __int_as_float(row)); }
        }
    }
}

// ---------------- D: one wave per column, Michelot + scatter --------------
__global__ __launch_bounds__(256, 4)
void k_solve(const int* __restrict__ cnt, const float2* __restrict__ cand,
             const float* __restrict__ x, const float* __restrict__ a,
             float* __restrict__ out)
{
    const int lane = threadIdx.x & 63;
    const int col  = blockIdx.x * 4 + (threadIdx.x >> 6);
    const int K    = cnt[col * CPAD];

    if (K <= CAPC) {
        float v = -3.3e38f; int row = 0;
        if (lane < K) {
            const float2 p = cand[(long)col * CAPC + lane];
            v = p.x; row = __float_as_int(p.y);
        }
        float t = -3.0e38f, prev = 0.f;
        for (int it = 0; it < CAPC + 4; ++it) {
            const bool act = v > t;
            float ss = act ? v : 0.f;
            float sc = act ? 1.f : 0.f;
#pragma unroll
            for (int m = 1; m < 64; m <<= 1) {
                ss += __shfl_xor(ss, m, 64);
                sc += __shfl_xor(sc, m, 64);
            }
            t = (ss - 1.0f) / sc;           // sc >= 1 (col max is a candidate)
            if (sc == prev) break;
            prev = sc;
        }
        if (v > t) out[(long)row * COLS + col] = v - t;   // out pre-zeroed
    } else {
        // overflow fallback: exact Michelot over the full column + scatter
        const float s = -expf(a[0]);
        float t = -3.0e38f, prev = 0.f;
        for (int it = 0; it < 256; ++it) {
            float ss = 0.f, sc = 0.f;
            for (int i = 0; i < ROWS / 64; ++i) {
                const float zz = s * x[(long)(lane + i * 64) * COLS + col];
                if (zz > t) { ss += zz; sc += 1.f; }
            }
#pragma unroll
            for (int m = 1; m < 64; m <<= 1) {
                ss += __shfl_xor(ss, m, 64);
                sc += __shfl_xor(sc, m, 64);
            }
            t = (ss - 1.0f) / sc;
            if (sc == prev) break;
            prev = sc;
        }
        for (int i = 0; i < ROWS / 64; ++i) {
            const long r = lane + i * 64;
            const float zz = s * x[r * COLS + col];
            if (zz > t) out[r * COLS + col] = zz - t;
        }
    }
}

extern "C" void kernel_launch(void* const* d_in, const int* in_sizes, int n_in,
                              void* d_out, int out_size, void* d_ws, size_t ws_size,
                              hipStream_t stream) {
    const float* x = (const float*)d_in[0];
    const float* a = (const float*)d_in[1];
    float* out = (float*)d_out;

    char*   ws    = (char*)d_ws;
    int*    cnt   = (int*)ws;                        // 512 KB (padded counters)
    float*  thrx  = (float*)(ws + 512 * 1024);       // 32 KB
    float*  pminx = (float*)(ws + 1024 * 1024);      // 8 MiB
    float2* cand  = (float2*)(ws + 9 * 1024 * 1024); // 4 MiB

    hipMemsetAsync(cnt, 0, COLS * CPAD * sizeof(int), stream);
    hipMemsetAsync(out, 0, (size_t)ROWS * COLS * sizeof(float), stream);
    hipLaunchKernelGGL(k_pmax,   dim3(NPA),        dim3(1024), 0, stream, x, pminx);
    hipLaunchKernelGGL(k_reduce, dim3(COLS / 32),  dim3(256),  0, stream, pminx, a, thrx);
    hipLaunchKernelGGL(k_filter, dim3(ROWS / PANC),dim3(512),  0, stream, x, a, thrx, cnt, cand);
    hipLaunchKernelGGL(k_solve,  dim3(COLS / 4),   dim3(256),  0, stream, cnt, cand, x, a, out);
}